// Round 11
// baseline (317.769 us; speedup 1.0000x reference)
//
#include <hip/hip_runtime.h>

// BKT 2-state HMM forward-backward. Prob-domain, zero-barrier, two-sweep.
// B=8192 chains, T=1024. One chain per wave (64 lanes = 64 chunks of KC=16).
// GG=4 chains/block (256 threads), grid 2048.
//
// ROUND 11: register-pressure cut + occupancy raise. The r5/r6 counters
// proved the allocator will spill ~30 floats/thread when its budget is 64
// (16 KB LDS -> 8 waves/EU target); r7's "fix" was never verified (kernel
// fell out of profiler top-5). This version removes the sm0/sm1 posterior
// arrays entirely (out1/P4 recompute s_i = ey_i * A[q] from the stored
// normalized forward state A[16]) -> live arrays = ey(32) + A(16) = 48 regs,
// ~75 live total. __launch_bounds__(256,5) sets a 102-VGPR budget (zero
// spill guaranteed) and 5 blocks/CU = 20 waves/CU (LDS 32 KB x 5 = 160 KB).
//
//  P1: obs/corr -> regs (single HBM read); sigmoids g -> gx/gy; per-lane
//      chunk composite F = prod L*diag(ey), exponent-strip renorm every 4.
//  P2: dual Kogge-Stone scan (8 FMA + renorm per level); alpha entry
//      (normalized A0 + log2-scale C), beta entry (normalized b0).
//  P3: forward sweep: A[q] saved; pred staged -> NT writeout; gx/gy
//      overwritten with selected emissions ey for out1/P4.
//  out1: s_i = ey_i*A[q]; log2(s_i)+Cr staged -> writeout (Cr running).
//  P4: backward sweep: smoothed = normalize(ey_i*A_i*b_i); beta recursion
//      prob-domain, rcp-normalized per step.

#define BB 8192
#define TT 1024
#define KC 16               // steps per chunk
#define NC 64               // chunks per chain == lanes per wave
#define GG 4                // chains per block (1 per wave)
#define NTHREADS (GG * NC)  // 256
#define LOG2E 1.4426950408889634f
#define LN2   0.6931471805599453f

typedef float floatx4 __attribute__((ext_vector_type(4)));

__device__ __forceinline__ float fexp2(float x) {
    return __builtin_amdgcn_exp2f(x);       // v_exp_f32 (base-2)
}
__device__ __forceinline__ float flog2(float x) {
    return __builtin_amdgcn_logf(x);        // v_log_f32 (base-2)
}
__device__ __forceinline__ float frcp(float x) {
    return __builtin_amdgcn_rcpf(x);        // v_rcp_f32
}
__device__ __forceinline__ unsigned umax2(unsigned a, unsigned b) {
    return a > b ? a : b;
}

__global__ __launch_bounds__(NTHREADS, 5) void bkt_kernel(
        const int* __restrict__ corr,
        const float* __restrict__ dyn,
        const float* __restrict__ obs,
        float* __restrict__ out) {
    __shared__ floatx4 st[GG][NC][8];   // 32 KB staging (one stream at a time)

    const int tid = threadIdx.x;
    const int g = tid >> 6;          // chain within block == wave id
    const int c = tid & (NC - 1);    // chunk index == lane
    const int b = blockIdx.x * GG + g;

    // transition probs (column-stochastic): l00=sig(-d0), l10=sig(d0),
    // l01=sig(d1), l11=sig(-d1); init: ai0=sig(-d2), ai1=sig(d2).
    const float d0 = dyn[b * 3 + 0] * LOG2E;
    const float d1 = dyn[b * 3 + 1] * LOG2E;
    const float d2 = dyn[b * 3 + 2] * LOG2E;
    const float ua = fexp2(d0);  const float ra = frcp(1.0f + ua);
    const float l00 = ra,        l10 = ua * ra;
    const float ub = fexp2(-d1); const float rb = frcp(1.0f + ub);
    const float l01v = rb,       l11 = ub * rb;
    const float uc = fexp2(d2);  const float rc2 = frcp(1.0f + uc);
    const float ai0 = rc2,       ai1 = uc * rc2;
    const float dl0 = l00 - l01v;

    const long long cb = (long long)b * TT + c * KC;  // chunk base (float2 idx)
    const float2* obs2 = (const float2*)obs;
    const long long S4 = (long long)BB * 512;         // float4 per stream
    floatx4* o0 = (floatx4*)out;        // pred logprobs
    floatx4* o1 = o0 + S4;              // state posteriors (log-joint)
    floatx4* o2 = o1 + S4;              // smoothed

    // ---------------- P1: load, sigmoids, fwd chunk composite (prob) ---------
    float gx[16], gy[16];   // sigmoids in P1..P3; emissions ey after P3
    unsigned ybits = 0;
    float F00, F01, F10, F11;
    int kF = 0;
    {
        const float4* op = (const float4*)(obs2 + cb);
        const int4* yp = (const int4*)(corr + cb);
        #pragma unroll
        for (int j = 0; j < 4; ++j) {
            int4 y4 = yp[j];
            ybits |= (unsigned)(y4.x & 1) << (4 * j + 0);
            ybits |= (unsigned)(y4.y & 1) << (4 * j + 1);
            ybits |= (unsigned)(y4.z & 1) << (4 * j + 2);
            ybits |= (unsigned)(y4.w & 1) << (4 * j + 3);
        }
        #pragma unroll
        for (int j = 0; j < 8; ++j) {
            float4 o4 = op[j];
            float lx0 = o4.x * LOG2E, ly0 = o4.y * LOG2E;
            float lx1 = o4.z * LOG2E, ly1 = o4.w * LOG2E;
            #pragma unroll
            for (int r2 = 0; r2 < 2; ++r2) {
                const int q = 2 * j + r2;
                float lx = r2 ? lx1 : lx0, ly = r2 ? ly1 : ly0;
                float u0 = fexp2(-lx); float r0 = frcp(1.0f + u0);  // g0=sig(lx)
                float u1 = fexp2(-ly); float r1 = frcp(1.0f + u1);  // g1=sig(ly)
                gx[q] = r0; gy[q] = r1;
                int y = (ybits >> q) & 1;
                float ey0 = y ? r0 : u0 * r0;        // p(y_q | h=0)
                float ey1 = y ? u1 * r1 : r1;        // p(y_q | h=1)
                if (q == 0) {
                    F00 = l00 * ey0; F01 = l01v * ey1;
                    F10 = l10 * ey0; F11 = l11 * ey1;
                } else {   // F := L * diag(ey) * F
                    float R00 = ey0 * F00, R01 = ey0 * F01;
                    float R10 = ey1 * F10, R11 = ey1 * F11;
                    F00 = l00 * R00 + l01v * R10;
                    F01 = l00 * R01 + l01v * R11;
                    F10 = l10 * R00 + l11 * R10;
                    F11 = l10 * R01 + l11 * R11;
                }
                if ((q & 3) == 3) {   // exponent-strip renorm (no trans ops)
                    unsigned bm = umax2(umax2(__float_as_uint(F00), __float_as_uint(F01)),
                                        umax2(__float_as_uint(F10), __float_as_uint(F11)));
                    int e = (int)(bm >> 23);
                    float sc = __uint_as_float((unsigned)(254 - e) << 23);
                    F00 *= sc; F01 *= sc; F10 *= sc; F11 *= sc;
                    kF += e - 127;
                }
            }
        }
    }

    // ---------------- P2: dual Kogge-Stone scan (prob, mant+exp) -------------
    float Gm00 = F00, Gm01 = F01, Gm10 = F10, Gm11 = F11;
    int kG = kF;
    float Hm00 = __shfl_down(F00, 1);
    float Hm01 = __shfl_down(F10, 1);   // transpose while shuffling
    float Hm10 = __shfl_down(F01, 1);
    float Hm11 = __shfl_down(F11, 1);
    if (c == NC - 1) { Hm00 = 1.0f; Hm01 = 0.0f; Hm10 = 0.0f; Hm11 = 1.0f; }
    #pragma unroll
    for (int dlv = 0; dlv < 6; ++dlv) {
        const int off = 1 << dlv;
        float u00 = __shfl_up(Gm00, off), u01 = __shfl_up(Gm01, off);
        float u10 = __shfl_up(Gm10, off), u11 = __shfl_up(Gm11, off);
        int ku = __shfl_up(kG, off);
        float n00 = Gm00 * u00 + Gm01 * u10;
        float n01 = Gm00 * u01 + Gm01 * u11;
        float n10 = Gm10 * u00 + Gm11 * u10;
        float n11 = Gm10 * u01 + Gm11 * u11;
        int kn = kG + ku;
        unsigned bm = umax2(umax2(__float_as_uint(n00), __float_as_uint(n01)),
                            umax2(__float_as_uint(n10), __float_as_uint(n11)));
        int e = (int)(bm >> 23);
        float sc = __uint_as_float((unsigned)(254 - e) << 23);
        n00 *= sc; n01 *= sc; n10 *= sc; n11 *= sc; kn += e - 127;
        bool dg = (c >= off);
        Gm00 = dg ? n00 : Gm00; Gm01 = dg ? n01 : Gm01;
        Gm10 = dg ? n10 : Gm10; Gm11 = dg ? n11 : Gm11;
        kG = dg ? kn : kG;
        float v00 = __shfl_down(Hm00, off), v01 = __shfl_down(Hm01, off);
        float v10 = __shfl_down(Hm10, off), v11 = __shfl_down(Hm11, off);
        float h00 = Hm00 * v00 + Hm01 * v10;
        float h01 = Hm00 * v01 + Hm01 * v11;
        float h10 = Hm10 * v00 + Hm11 * v10;
        float h11 = Hm10 * v01 + Hm11 * v11;
        unsigned bh = umax2(umax2(__float_as_uint(h00), __float_as_uint(h01)),
                            umax2(__float_as_uint(h10), __float_as_uint(h11)));
        int eh = (int)(bh >> 23);
        float sch = __uint_as_float((unsigned)(254 - eh) << 23);
        h00 *= sch; h01 *= sch; h10 *= sch; h11 *= sch;   // scale-free: drop k
        bool dh = (c + off < NC);
        Hm00 = dh ? h00 : Hm00; Hm01 = dh ? h01 : Hm01;
        Hm10 = dh ? h10 : Hm10; Hm11 = dh ? h11 : Hm11;
    }
    // alpha at chunk entry: G_{c-1} * a_init, normalized + C (log2 scale)
    float Pm00 = __shfl_up(Gm00, 1), Pm01 = __shfl_up(Gm01, 1);
    float Pm10 = __shfl_up(Gm10, 1), Pm11 = __shfl_up(Gm11, 1);
    int kP = __shfl_up(kG, 1);
    float am0 = Pm00 * ai0 + Pm01 * ai1;
    float am1 = Pm10 * ai0 + Pm11 * ai1;
    float nrma = am0 + am1;
    float A0 = (c == 0) ? ai0 : am0 * frcp(nrma);
    float C  = (c == 0) ? 0.0f : (float)kP + flog2(nrma);
    // beta at chunk end: L^T * (H * 1), normalized (scale-free)
    float w0 = Hm00 + Hm01, w1 = Hm10 + Hm11;
    float b0u = l00 * w0 + l10 * w1;
    float b1u = l01v * w0 + l11 * w1;
    float b0 = b0u * frcp(b0u + b1u);

    const long long bb4 = (long long)b * 512;   // float4 base of this chain
    const int sw = c & 7;                       // slot swizzle

    // ---------------- P3: forward sweep (prob): pred; A[q] saved -------------
    float A[16];   // normalized forward state at each step entry
    {
        float e0a, e1a;
        #pragma unroll
        for (int q = 0; q < 16; ++q) {
            float g0 = gx[q], g1 = gy[q];
            float h0 = 1.0f - g0, h1 = 1.0f - g1;
            float A1v = 1.0f - A0;
            A[q] = A0;
            float pr0 = h0 * A0 + g1 * A1v;     // p(y=0 | y_<t); pr0+pr1=1
            float pr1 = 1.0f - pr0;
            float wo0 = flog2(pr0) * LN2, wo1 = flog2(pr1) * LN2;
            int y = (ybits >> q) & 1;
            float ey0 = y ? g0 : h0;
            float ey1 = y ? h1 : g1;
            gx[q] = ey0; gy[q] = ey1;           // out1/P4 need ey only
            float s0 = ey0 * A0, s1 = ey1 * A1v;
            float t0 = s0 * frcp(s0 + s1);
            A0 = l01v + t0 * dl0;               // L * t (normalized)
            if (q & 1) st[g][c][(q >> 1) ^ sw] = (floatx4){e0a, e1a, wo0, wo1};
            else       { e0a = wo0; e1a = wo1; }
        }
    }
    #pragma unroll
    for (int i = 0; i < 8; ++i) {
        int flat = i * 64 + c;
        int c2 = flat >> 3, k2 = flat & 7;
        floatx4 v = st[g][c2][k2 ^ (c2 & 7)];
        __builtin_nontemporal_store(v, o0 + bb4 + flat);
    }
    // out1 staging: s_i = ey_i * A[q]; log2(s_i) + Cr (running), *LN2
    {
        float Cr = C;
        float e0a, e1a;
        #pragma unroll
        for (int q = 0; q < 16; ++q) {
            float a0q = A[q];
            float s0 = gx[q] * a0q, s1 = gy[q] * (1.0f - a0q);
            float v0 = (flog2(s0) + Cr) * LN2;
            float v1 = (flog2(s1) + Cr) * LN2;
            Cr += flog2(s0 + s1);
            if (q & 1) st[g][c][(q >> 1) ^ sw] = (floatx4){e0a, e1a, v0, v1};
            else       { e0a = v0; e1a = v1; }
        }
    }
    #pragma unroll
    for (int i = 0; i < 8; ++i) {
        int flat = i * 64 + c;
        int c2 = flat >> 3, k2 = flat & 7;
        floatx4 v = st[g][c2][k2 ^ (c2 & 7)];
        __builtin_nontemporal_store(v, o1 + bb4 + flat);
    }

    // ---------------- P4: backward sweep (prob): smoothed --------------------
    {
        float o0s, o1s;
        #pragma unroll
        for (int q = 15; q >= 0; --q) {
            float a0q = A[q];
            float b1v = 1.0f - b0;
            float ey0 = gx[q], ey1 = gy[q];
            float gg0 = ey0 * a0q * b0, gg1 = ey1 * (1.0f - a0q) * b1v;
            float lgs = flog2(gg0 + gg1);
            float w20 = (flog2(gg0) - lgs) * LN2;
            float w21 = (flog2(gg1) - lgs) * LN2;
            float m0 = ey0 * b0, m1 = ey1 * b1v;
            float nb0 = l00 * m0 + l10 * m1;
            float nb1 = l01v * m0 + l11 * m1;
            b0 = nb0 * frcp(nb0 + nb1);
            if (q & 1) { o0s = w20; o1s = w21; }
            else       st[g][c][(q >> 1) ^ sw] = (floatx4){w20, w21, o0s, o1s};
        }
    }
    #pragma unroll
    for (int i = 0; i < 8; ++i) {
        int flat = i * 64 + c;
        int c2 = flat >> 3, k2 = flat & 7;
        floatx4 v = st[g][c2][k2 ^ (c2 & 7)];
        __builtin_nontemporal_store(v, o2 + bb4 + flat);
    }
}

extern "C" void kernel_launch(void* const* d_in, const int* in_sizes, int n_in,
                              void* d_out, int out_size, void* d_ws, size_t ws_size,
                              hipStream_t stream) {
    const int*   corr = (const int*)d_in[0];
    const float* dyn  = (const float*)d_in[1];
    const float* obs  = (const float*)d_in[2];
    float* out = (float*)d_out;

    dim3 block(NTHREADS);            // 256 = 4 chains x 64 chunks
    dim3 grid(BB / GG);              // 2048 blocks
    bkt_kernel<<<grid, block, 0, stream>>>(corr, dyn, obs, out);
}